// Round 13
// baseline (472.691 us; speedup 1.0000x reference)
//
#include <hip/hip_runtime.h>

#define N_D 128
#define N_H 256
#define EPSV 1e-5f
#define STAT_ROWS 256
#define NS1 16     // xstats slices
#define NS2 32     // gemm1-stats slices
#define NB 1024    // row-range buckets
#define PERB 2304  // staged capacity per bucket (mean 1563, +18 sigma)
#define CPAD 16    // cursor padding: one counter per 64B line

typedef unsigned short u16;
typedef __attribute__((ext_vector_type(8))) short short8;
typedef __attribute__((ext_vector_type(4))) float floatx4;

__device__ __forceinline__ float bf2f(unsigned u) {
    return __uint_as_float(u << 16);
}
__device__ __forceinline__ u16 f2bf(float f) {
    unsigned u = __float_as_uint(f);
    return (u16)((u + 0x7FFFu + ((u >> 16) & 1u)) >> 16);
}

// ------- convert input fp32 -> xbf cols 0..127 (bf16); no atomics -------
__global__ __launch_bounds__(256) void convin_kernel(
    const float* __restrict__ input, u16* __restrict__ xbf, int n)
{
    int gid = blockIdx.x * 256 + threadIdx.x;
    if (gid < n * 32) {
        int r = gid >> 5, c4 = (gid & 31) * 4;
        float4 v = *(const float4*)&input[(size_t)r * N_D + c4];
        unsigned p0 = f2bf(v.x) | ((unsigned)f2bf(v.y) << 16);
        unsigned p1 = f2bf(v.z) | ((unsigned)f2bf(v.w) << 16);
        *(uint2*)&xbf[(size_t)r * 256 + c4] = make_uint2(p0, p1);
    }
}

// ------- bucket edges by row-range; ONE global atomic per (block,bucket). -------
__global__ __launch_bounds__(1024) void bucket_kernel(
    const int* __restrict__ rows, const int* __restrict__ cols,
    const float* __restrict__ vals, int* __restrict__ cursor,
    int2* __restrict__ staged, int E, unsigned inv_pr, int per_rows)
{
    __shared__ int hist[NB];
    __shared__ int base[NB];
    __shared__ int lcnt[NB];
    int t = threadIdx.x;
    hist[t] = 0;
    __syncthreads();
    int per = (E + (int)gridDim.x - 1) / (int)gridDim.x;
    int lo = blockIdx.x * per;
    int hi = min(E, lo + per);
    for (int e = lo + t; e < hi; e += 1024) {
        int b = (int)__umulhi((unsigned)rows[e], inv_pr);
        atomicAdd(&hist[b], 1);
    }
    __syncthreads();
    {
        int h = hist[t];
        base[t] = h ? atomicAdd(&cursor[t * CPAD], h) : 0;
        lcnt[t] = 0;
    }
    __syncthreads();
    for (int e = lo + t; e < hi; e += 1024) {
        int r = rows[e];
        int b = (int)__umulhi((unsigned)r, inv_pr);
        int rl = r - b * per_rows;                       // < 98, 7 bits
        int idx = base[b] + atomicAdd(&lcnt[b], 1);      // LDS cursor
        if (idx < PERB)                                  // P(overflow) ~ 1e-30
            staged[(size_t)b * PERB + idx] =
                make_int2(cols[e] | (rl << 17), __float_as_int(vals[e]));
    }
}

// ------- exclusive scan of 1024 bucket counts -> bucketBase -------
__global__ __launch_bounds__(1024) void scan_buckets_kernel(
    const int* __restrict__ cursor, int* __restrict__ bucketBase)
{
    __shared__ int sm[NB];
    int t = threadIdx.x;
    int v = min(cursor[t * CPAD], PERB);
    sm[t] = v;
    __syncthreads();
    for (int off = 1; off < NB; off <<= 1) {
        int x = (t >= off) ? sm[t - off] : 0;
        __syncthreads();
        sm[t] += x;
        __syncthreads();
    }
    bucketBase[t] = sm[t] - v;
}

// ------- place: block per bucket; LDS histogram+scan -> CSR edges/rowPtr/cnt -------
__global__ __launch_bounds__(256) void place_kernel(
    const int* __restrict__ cursor, const int* __restrict__ bucketBase,
    const int2* __restrict__ staged, int2* __restrict__ edges,
    int* __restrict__ rowPtr, int* __restrict__ cnt, int n, int per_rows)
{
    __shared__ int hist[128];
    __shared__ int scn[128];
    __shared__ int lcnt[128];
    int b = blockIdx.x;
    int t = threadIdx.x;
    int r0 = b * per_rows;
    if (r0 >= n) return;
    if (t < 128) { hist[t] = 0; lcnt[t] = 0; }
    __syncthreads();
    int count = min(cursor[b * CPAD], PERB);
    const int2* sb = staged + (size_t)b * PERB;
    for (int i = t; i < count; i += 256)
        atomicAdd(&hist[((unsigned)sb[i].x) >> 17], 1);
    __syncthreads();
    if (t < 128) scn[t] = hist[t];
    __syncthreads();
    for (int off = 1; off < 128; off <<= 1) {
        int x = (t < 128 && t >= off) ? scn[t - off] : 0;
        __syncthreads();
        if (t < 128) scn[t] += x;
        __syncthreads();
    }
    int base = bucketBase[b];
    if (t < per_rows && r0 + t < n) {
        rowPtr[r0 + t] = base + scn[t] - hist[t];   // exclusive
        cnt[r0 + t] = hist[t];
    }
    __syncthreads();
    for (int i = t; i < count; i += 256) {
        int2 en = sb[i];
        int rl = ((unsigned)en.x) >> 17;
        int idx = atomicAdd(&lcnt[rl], 1);
        edges[base + scn[rl] - hist[rl] + idx] = make_int2(en.x & 0x1FFFF, en.y);
    }
}

// ------- gather-reduce: 2 edges per wave (half-wave each, uint2 gathers). -------
__global__ __launch_bounds__(256) void aggregate_kernel(
    const unsigned* __restrict__ xin,
    const int* __restrict__ rowPtr, const int* __restrict__ cnt,
    const int2* __restrict__ edges,
    unsigned* __restrict__ xout, int n)
{
    int wave = (blockIdx.x * 256 + threadIdx.x) >> 6;
    if (wave >= n) return;
    int lane = threadIdx.x & 63;
    int half = lane >> 5;
    int ll = lane & 31;
    const uint2* xin2 = (const uint2*)xin;      // row stride 64 uint2
    int e = rowPtr[wave];
    int end = e + cnt[wave];
    float4 a0 = {0.f,0.f,0.f,0.f}, a1 = {0.f,0.f,0.f,0.f};
    float4 a2 = {0.f,0.f,0.f,0.f}, a3 = {0.f,0.f,0.f,0.f};

#define ACC4(acc, pp, vv) { \
        acc.x += (vv) * bf2f((pp).x & 0xFFFF); \
        acc.y += (vv) * bf2f((pp).x >> 16); \
        acc.z += (vv) * bf2f((pp).y & 0xFFFF); \
        acc.w += (vv) * bf2f((pp).y >> 16); }

    if ((e & 1) && e < end) {
        int2 ed = edges[e];
        float v = half ? 0.f : __int_as_float(ed.y);
        uint2 p = xin2[(size_t)ed.x * 64 + ll];
        ACC4(a0, p, v);
        ++e;
    }
    for (; e + 7 < end; e += 8) {
        int4 q0 = *(const int4*)&edges[e];
        int4 q1 = *(const int4*)&edges[e + 2];
        int4 q2 = *(const int4*)&edges[e + 4];
        int4 q3 = *(const int4*)&edges[e + 6];
        int   c0 = half ? q0.z : q0.x;
        int   c1 = half ? q1.z : q1.x;
        int   c2 = half ? q2.z : q2.x;
        int   c3 = half ? q3.z : q3.x;
        float v0 = __int_as_float(half ? q0.w : q0.y);
        float v1 = __int_as_float(half ? q1.w : q1.y);
        float v2 = __int_as_float(half ? q2.w : q2.y);
        float v3 = __int_as_float(half ? q3.w : q3.y);
        uint2 p0 = xin2[(size_t)c0 * 64 + ll];
        uint2 p1 = xin2[(size_t)c1 * 64 + ll];
        uint2 p2 = xin2[(size_t)c2 * 64 + ll];
        uint2 p3 = xin2[(size_t)c3 * 64 + ll];
        ACC4(a0, p0, v0);
        ACC4(a1, p1, v1);
        ACC4(a2, p2, v2);
        ACC4(a3, p3, v3);
    }
    for (; e + 1 < end; e += 2) {
        int4 q0 = *(const int4*)&edges[e];
        int   c0 = half ? q0.z : q0.x;
        float v0 = __int_as_float(half ? q0.w : q0.y);
        uint2 p0 = xin2[(size_t)c0 * 64 + ll];
        ACC4(a0, p0, v0);
    }
    if (e < end) {
        int2 ed = edges[e];
        float v = half ? 0.f : __int_as_float(ed.y);
        uint2 p = xin2[(size_t)ed.x * 64 + ll];
        ACC4(a0, p, v);
    }
#undef ACC4

    a0.x += a1.x + a2.x + a3.x;
    a0.y += a1.y + a2.y + a3.y;
    a0.z += a1.z + a2.z + a3.z;
    a0.w += a1.w + a2.w + a3.w;
    float bx = __shfl(a0.x, ll + 32, 64);
    float by = __shfl(a0.y, ll + 32, 64);
    float bz = __shfl(a0.z, ll + 32, 64);
    float bw = __shfl(a0.w, ll + 32, 64);
    if (half == 0) {
        a0.x += bx; a0.y += by; a0.z += bz; a0.w += bw;
        uint2 pk;
        pk.x = f2bf(a0.x) | ((unsigned)f2bf(a0.y) << 16);
        pk.y = f2bf(a0.z) | ((unsigned)f2bf(a0.w) << 16);
        ((uint2*)xout)[(size_t)wave * 64 + 32 + ll] = pk;
    }
}

// ------------- column sums/sumsq of xbf, SLICED accumulators -------------
__global__ __launch_bounds__(256) void xstats_kernel(
    const u16* __restrict__ xbf, float* __restrict__ s1s, int n)
{
    int t = threadIdx.x;
    int r0 = blockIdx.x * STAT_ROWS;
    int r1 = min(n, r0 + STAT_ROWS);
    float s = 0.f, q = 0.f;
    for (int r = r0; r < r1; ++r) {
        float x = bf2f((unsigned)xbf[(size_t)r * 256 + t]);
        s += x; q += x * x;
    }
    float* base = s1s + (size_t)(blockIdx.x & (NS1 - 1)) * 512;
    atomicAdd(&base[t], s);
    atomicAdd(&base[256 + t], q);
}

// ------------- BN1 affine coefficients (reduces NS1 slices) -------------
__global__ __launch_bounds__(256) void prep1a_kernel(
    const float* __restrict__ s1s,
    const float* __restrict__ gamma1, const float* __restrict__ beta1,
    float* __restrict__ a1, float* __restrict__ c1, float n)
{
    int t = threadIdx.x;
    float sum = 0.f, sq = 0.f;
#pragma unroll
    for (int s = 0; s < NS1; ++s) {
        sum += s1s[s * 512 + t];
        sq  += s1s[s * 512 + 256 + t];
    }
    float mu = sum / n;
    float var = sq / n - mu * mu;
    float rs = rsqrtf(var + EPSV);
    float a = rs * gamma1[t];
    a1[t] = a;
    c1[t] = beta1[t] - mu * a;
}

// ------- W1bt[nIdx][k] = bf16(a1[k]*W1[k][nIdx]) ; b1p = c1@W1 + b1 -------
__global__ __launch_bounds__(256) void convw1_kernel(
    const float* __restrict__ W1, const float* __restrict__ a1,
    const float* __restrict__ c1, const float* __restrict__ b1,
    u16* __restrict__ W1bt, float* __restrict__ b1p)
{
    __shared__ float red[256];
    int nIdx = blockIdx.x;
    int k = threadIdx.x;
    float w = W1[(size_t)k * N_H + nIdx];
    W1bt[(size_t)nIdx * 256 + k] = f2bf(a1[k] * w);
    red[k] = c1[k] * w;
    __syncthreads();
    for (int s = 128; s > 0; s >>= 1) {
        if (k < s) red[k] += red[k + s];
        __syncthreads();
    }
    if (k == 0) b1p[nIdx] = red[0] + b1[nIdx];
}

// ------------- W2bt[nIdx][k] = bf16(W2[k][nIdx]) -------------
__global__ __launch_bounds__(256) void convw2_kernel(
    const float* __restrict__ W2, u16* __restrict__ W2bt)
{
    int nIdx = blockIdx.x;
    int k = threadIdx.x;
    W2bt[(size_t)nIdx * 256 + k] = f2bf(W2[(size_t)k * N_D + nIdx]);
}

// ------------- BN2 per-column affine (reduces NS2 slices) -------------
__global__ __launch_bounds__(256) void prep2_kernel(
    const float* __restrict__ s2s,
    const float* __restrict__ gamma2, const float* __restrict__ beta2,
    float* __restrict__ a2, float* __restrict__ c2, float n)
{
    int t = threadIdx.x;
    float sum = 0.f, sq = 0.f;
#pragma unroll
    for (int s = 0; s < NS2; ++s) {
        sum += s2s[s * 512 + t];
        sq  += s2s[s * 512 + 256 + t];
    }
    float mu = sum / n;
    float var = sq / n - mu * mu;
    float rs = rsqrtf(var + EPSV);
    float a = rs * gamma2[t];
    a2[t] = a;
    c2[t] = beta2[t] - mu * a;
}

// ------------- GEMM1: bulk-load K-half then MFMA burst.
// R12 A/B refuted occupancy theory (occ 23->37%, dur flat). VGPR_Count=52
// (< the 128 regs the fragments need) shows the compiler recycled the
// double-buffer regs -> every load->use pair serialized at full latency
// (~54 chains/wave ~ 5-6us/wave = the invariant ~80-90us). Here all 24
// loads of a K=128 half are issued before any MFMA touches them ->
// latency paid ~once per half. -------------
__global__ __launch_bounds__(256, 3) void gemm1_kernel(
    const u16* __restrict__ xbf, const u16* __restrict__ W1bt,
    const float* __restrict__ b1p, u16* __restrict__ ybf,
    float* __restrict__ s2s, int n)
{
    __shared__ __align__(16) u16 T[64 * 136];   // +8 pad per row
    __shared__ float ssum[128];
    __shared__ float ssq[128];
    int t = threadIdx.x;
    int w = t >> 6, l = t & 63;
    int row0 = blockIdx.x * 64;
    int col0 = blockIdx.y * 128;
    int wrow = (w & 1) * 32, wcol = (w >> 1) * 64;
    int lm = l & 15, lq = l >> 4;
    if (t < 128) { ssum[t] = 0.f; ssq[t] = 0.f; }

    floatx4 acc[2][4];
#pragma unroll
    for (int i = 0; i < 2; ++i)
#pragma unroll
        for (int j = 0; j < 4; ++j) acc[i][j] = (floatx4){0.f, 0.f, 0.f, 0.f};

    const u16* Ab = xbf + (size_t)(row0 + wrow + lm) * 256 + lq * 8;
    const u16* Bb = W1bt + (size_t)(col0 + wcol + lm) * 256 + lq * 8;

#pragma unroll
    for (int h = 0; h < 2; ++h) {
        const int kh = h * 128;
        short8 aR[4][2], bR[4][4];
#pragma unroll
        for (int s = 0; s < 4; ++s) {
            int k = kh + s * 32;
            aR[s][0] = *(const short8*)&Ab[k];
            aR[s][1] = *(const short8*)&Ab[4096 + k];
            bR[s][0] = *(const short8*)&Bb[k];
            bR[s][1] = *(const short8*)&Bb[4096 + k];
            bR[s][2] = *(const short8*)&Bb[8192 + k];
            bR[s][3] = *(const short8*)&Bb[12288 + k];
        }
#pragma unroll
        for (int s = 0; s < 4; ++s)
#pragma unroll
            for (int fm = 0; fm < 2; ++fm)
#pragma unroll
                for (int fn = 0; fn < 4; ++fn)
                    acc[fm][fn] = __builtin_amdgcn_mfma_f32_16x16x32_bf16(
                        aR[s][fm], bR[s][fn], acc[fm][fn], 0, 0, 0);
    }

    __syncthreads();   // orders ssum/ssq init before atomics below
    float cs[4] = {0.f, 0.f, 0.f, 0.f};
    float cq[4] = {0.f, 0.f, 0.f, 0.f};
#pragma unroll
    for (int fn = 0; fn < 4; ++fn) {
        int cl = wcol + fn * 16 + lm;
        float bb = b1p[col0 + cl];
#pragma unroll
        for (int fm = 0; fm < 2; ++fm) {
            int rl = wrow + fm * 16 + lq * 4;
#pragma unroll
            for (int i = 0; i < 4; ++i) {
                float v = acc[fm][fn][i] + bb;
                T[(rl + i) * 136 + cl] = f2bf(v);
                if (row0 + rl + i < n) { cs[fn] += v; cq[fn] += v * v; }
            }
        }
        atomicAdd(&ssum[cl], cs[fn]);
        atomicAdd(&ssq[cl], cq[fn]);
    }
    __syncthreads();
    float* sbase = s2s + (size_t)(blockIdx.x & (NS2 - 1)) * 512;
    if (t < 128) {
        atomicAdd(&sbase[col0 + t], ssum[t]);
        atomicAdd(&sbase[256 + col0 + t], ssq[t]);
    }
    // coalesced writeback: 16 lanes x uint4 = one full 256B row-half per pass
#pragma unroll
    for (int p = 0; p < 4; ++p) {
        int r = p * 16 + (t >> 4);
        if (row0 + r < n)
            *(uint4*)&ybf[(size_t)(row0 + r) * 256 + col0 + (t & 15) * 8] =
                *(const uint4*)&T[r * 136 + (t & 15) * 8];
    }
}

__device__ __forceinline__ short8 bn_relu_pack(
    uint4 raw, float4 aa0, float4 aa1, float4 cc0, float4 cc1)
{
    float z0 = fmaxf(bf2f(raw.x & 0xFFFF) * aa0.x + cc0.x, 0.f);
    float z1 = fmaxf(bf2f(raw.x >> 16)    * aa0.y + cc0.y, 0.f);
    float z2 = fmaxf(bf2f(raw.y & 0xFFFF) * aa0.z + cc0.z, 0.f);
    float z3 = fmaxf(bf2f(raw.y >> 16)    * aa0.w + cc0.w, 0.f);
    float z4 = fmaxf(bf2f(raw.z & 0xFFFF) * aa1.x + cc1.x, 0.f);
    float z5 = fmaxf(bf2f(raw.z >> 16)    * aa1.y + cc1.y, 0.f);
    float z6 = fmaxf(bf2f(raw.w & 0xFFFF) * aa1.z + cc1.z, 0.f);
    float z7 = fmaxf(bf2f(raw.w >> 16)    * aa1.w + cc1.w, 0.f);
    uint4 pk;
    pk.x = f2bf(z0) | ((unsigned)f2bf(z1) << 16);
    pk.y = f2bf(z2) | ((unsigned)f2bf(z3) << 16);
    pk.z = f2bf(z4) | ((unsigned)f2bf(z5) << 16);
    pk.w = f2bf(z6) | ((unsigned)f2bf(z7) << 16);
    return *(short8*)&pk;
}

// ------------- GEMM2: bulk-load K-half then convert+MFMA burst.
// (256,2): BN tables add register pressure; 256-reg budget guarantees
// the 24-load bulk stays in registers (no spill, no serialization). -------------
__global__ __launch_bounds__(256, 2) void gemm2_kernel(
    const u16* __restrict__ ybf, const u16* __restrict__ W2bt,
    const float* __restrict__ a2, const float* __restrict__ c2,
    const float* __restrict__ b2, float* __restrict__ out, int n)
{
    int t = threadIdx.x;
    int w = t >> 6, l = t & 63;
    int row0 = blockIdx.x * 64;
    int wrow = (w & 1) * 32, wcol = (w >> 1) * 64;
    int lm = l & 15, lq = l >> 4;

    floatx4 acc[2][4];
#pragma unroll
    for (int i = 0; i < 2; ++i)
#pragma unroll
        for (int j = 0; j < 4; ++j) acc[i][j] = (floatx4){0.f, 0.f, 0.f, 0.f};

    const u16* Ab = ybf + (size_t)(row0 + wrow + lm) * 256 + lq * 8;
    const u16* Bb = W2bt + (size_t)(wcol + lm) * 256 + lq * 8;
    int kbase = lq * 8;

#pragma unroll
    for (int h = 0; h < 2; ++h) {
        const int kh = h * 128;
        uint4 yR[4][2];
        short8 bR[4][4];
#pragma unroll
        for (int s = 0; s < 4; ++s) {
            int k = kh + s * 32;
            yR[s][0] = *(const uint4*)&Ab[k];
            yR[s][1] = *(const uint4*)&Ab[4096 + k];
            bR[s][0] = *(const short8*)&Bb[k];
            bR[s][1] = *(const short8*)&Bb[4096 + k];
            bR[s][2] = *(const short8*)&Bb[8192 + k];
            bR[s][3] = *(const short8*)&Bb[12288 + k];
        }
#pragma unroll
        for (int s = 0; s < 4; ++s) {
            int kc = kh + s * 32 + kbase;
            float4 aa0 = *(const float4*)&a2[kc];
            float4 aa1 = *(const float4*)&a2[kc + 4];
            float4 cc0 = *(const float4*)&c2[kc];
            float4 cc1 = *(const float4*)&c2[kc + 4];
            short8 af0 = bn_relu_pack(yR[s][0], aa0, aa1, cc0, cc1);
            short8 af1 = bn_relu_pack(yR[s][1], aa0, aa1, cc0, cc1);
#pragma unroll
            for (int fn = 0; fn < 4; ++fn) {
                acc[0][fn] = __builtin_amdgcn_mfma_f32_16x16x32_bf16(
                    af0, bR[s][fn], acc[0][fn], 0, 0, 0);
                acc[1][fn] = __builtin_amdgcn_mfma_f32_16x16x32_bf16(
                    af1, bR[s][fn], acc[1][fn], 0, 0, 0);
            }
        }
    }

#pragma unroll
    for (int fn = 0; fn < 4; ++fn) {
        int c = wcol + fn * 16 + lm;
        float bb = b2[c];
#pragma unroll
        for (int fm = 0; fm < 2; ++fm) {
            int rbase = row0 + wrow + fm * 16 + lq * 4;
#pragma unroll
            for (int i = 0; i < 4; ++i) {
                int r = rbase + i;
                if (r < n) out[(size_t)r * N_D + c] = acc[fm][fn][i] + bb;
            }
        }
    }
}

extern "C" void kernel_launch(void* const* d_in, const int* in_sizes, int n_in,
                              void* d_out, int out_size, void* d_ws, size_t ws_size,
                              hipStream_t stream)
{
    const float* input    = (const float*)d_in[0];
    const int*   adj_rows = (const int*)d_in[1];
    const int*   adj_cols = (const int*)d_in[2];
    const float* adj_vals = (const float*)d_in[3];
    const float* gamma1   = (const float*)d_in[4];
    const float* beta1    = (const float*)d_in[5];
    const float* W1       = (const float*)d_in[6];
    const float* b1       = (const float*)d_in[7];
    const float* gamma2   = (const float*)d_in[8];
    const float* beta2    = (const float*)d_in[9];
    const float* W2       = (const float*)d_in[10];
    const float* b2       = (const float*)d_in[11];

    int n = in_sizes[0] / N_D;   // 100000
    int E = in_sizes[1];         // 1600000
    size_t n_pad = ((size_t)n + 127) & ~(size_t)127;

    u16* xbf = (u16*)d_ws;                         // n_pad*256 bf16
    u16* ybf = xbf + n_pad * 256;                  // n_pad*256 bf16
    int2* edges = (int2*)ybf;                      // E int2 (aliases ybf; consumed pre-gemm1)
    int2* staged = edges + E;                      // NB*PERB int2 (also in ybf region)
    u16* W1bt = ybf + n_pad * 256;                 // 256*256 bf16
    u16* W2bt = W1bt + 256 * 256;                  // 128*256 bf16
    float* stats  = (float*)(W2bt + 128 * 256);
    float* a1     = stats;
    float* c1     = stats + 256;
    float* b1p    = stats + 512;
    float* a2     = stats + 768;
    float* c2     = stats + 1024;
    float* s1s    = stats + 1280;                  // NS1*512 floats
    float* s2s    = s1s + NS1 * 512;               // NS2*512 floats
    int* cursor     = (int*)(s2s + NS2 * 512);     // NB*CPAD ints (64B-padded)
    int* bucketBase = cursor + NB * CPAD;          // NB ints
    int* rowPtr     = bucketBase + NB;             // n ints
    int* cnt        = rowPtr + n;                  // n ints

    hipMemsetAsync(cursor, 0, (size_t)NB * CPAD * sizeof(int), stream);
    hipMemsetAsync(s1s, 0, (size_t)(NS1 + NS2) * 512 * sizeof(float), stream);

    convin_kernel<<<(n * 32 + 255) / 256, 256, 0, stream>>>(input, xbf, n);
    convw2_kernel<<<128, 256, 0, stream>>>(W2, W2bt);

    // bucket magic: b = umulhi(r, inv_pr) == r / per_rows for r < 2^17
    int per_rows = (n + NB - 1) / NB;                       // 98
    unsigned inv_pr = (unsigned)((((unsigned long long)1 << 32) + per_rows - 1) / per_rows);

    bucket_kernel<<<256, 1024, 0, stream>>>(
        adj_rows, adj_cols, adj_vals, cursor, staged, E, inv_pr, per_rows);
    scan_buckets_kernel<<<1, 1024, 0, stream>>>(cursor, bucketBase);
    place_kernel<<<NB, 256, 0, stream>>>(
        cursor, bucketBase, staged, edges, rowPtr, cnt, n, per_rows);

    aggregate_kernel<<<(n + 3) / 4, 256, 0, stream>>>(
        (const unsigned*)xbf, rowPtr, cnt, edges, (unsigned*)xbf, n);

    xstats_kernel<<<(n + STAT_ROWS - 1) / STAT_ROWS, 256, 0, stream>>>(xbf, s1s, n);

    prep1a_kernel<<<1, 256, 0, stream>>>(s1s, gamma1, beta1, a1, c1, (float)n);
    convw1_kernel<<<256, 256, 0, stream>>>(W1, a1, c1, b1, W1bt, b1p);

    dim3 g1((unsigned)(n_pad / 64), 2);
    gemm1_kernel<<<g1, 256, 0, stream>>>(xbf, W1bt, b1p, ybf, s2s, n);

    prep2_kernel<<<1, 256, 0, stream>>>(s2s, gamma2, beta2, a2, c2, (float)n);

    gemm2_kernel<<<(unsigned)(n_pad / 64), 256, 0, stream>>>(ybf, W2bt, a2, c2, b2, (float*)d_out, n);
}

// Round 14
// 471.396 us; speedup vs baseline: 1.0027x; 1.0027x over previous
//
#include <hip/hip_runtime.h>

#define N_D 128
#define N_H 256
#define EPSV 1e-5f
#define STAT_ROWS 256
#define NS1 16     // xstats slices
#define NS2 32     // gemm1-stats slices
#define NB 1024    // row-range buckets
#define PERB 2304  // staged capacity per bucket (mean 1563, +18 sigma)
#define CPAD 16    // cursor padding: one counter per 64B line

typedef unsigned short u16;
typedef __attribute__((ext_vector_type(8))) short short8;
typedef __attribute__((ext_vector_type(4))) float floatx4;

__device__ __forceinline__ float bf2f(unsigned u) {
    return __uint_as_float(u << 16);
}
__device__ __forceinline__ u16 f2bf(float f) {
    unsigned u = __float_as_uint(f);
    return (u16)((u + 0x7FFFu + ((u >> 16) & 1u)) >> 16);
}

// ------- convert input fp32 -> xbf cols 0..127 (bf16); no atomics -------
__global__ __launch_bounds__(256) void convin_kernel(
    const float* __restrict__ input, u16* __restrict__ xbf, int n)
{
    int gid = blockIdx.x * 256 + threadIdx.x;
    if (gid < n * 32) {
        int r = gid >> 5, c4 = (gid & 31) * 4;
        float4 v = *(const float4*)&input[(size_t)r * N_D + c4];
        unsigned p0 = f2bf(v.x) | ((unsigned)f2bf(v.y) << 16);
        unsigned p1 = f2bf(v.z) | ((unsigned)f2bf(v.w) << 16);
        *(uint2*)&xbf[(size_t)r * 256 + c4] = make_uint2(p0, p1);
    }
}

// ------- bucket edges by row-range; ONE global atomic per (block,bucket). -------
__global__ __launch_bounds__(1024) void bucket_kernel(
    const int* __restrict__ rows, const int* __restrict__ cols,
    const float* __restrict__ vals, int* __restrict__ cursor,
    int2* __restrict__ staged, int E, unsigned inv_pr, int per_rows)
{
    __shared__ int hist[NB];
    __shared__ int base[NB];
    __shared__ int lcnt[NB];
    int t = threadIdx.x;
    hist[t] = 0;
    __syncthreads();
    int per = (E + (int)gridDim.x - 1) / (int)gridDim.x;
    int lo = blockIdx.x * per;
    int hi = min(E, lo + per);
    for (int e = lo + t; e < hi; e += 1024) {
        int b = (int)__umulhi((unsigned)rows[e], inv_pr);
        atomicAdd(&hist[b], 1);
    }
    __syncthreads();
    {
        int h = hist[t];
        base[t] = h ? atomicAdd(&cursor[t * CPAD], h) : 0;
        lcnt[t] = 0;
    }
    __syncthreads();
    for (int e = lo + t; e < hi; e += 1024) {
        int r = rows[e];
        int b = (int)__umulhi((unsigned)r, inv_pr);
        int rl = r - b * per_rows;                       // < 98, 7 bits
        int idx = base[b] + atomicAdd(&lcnt[b], 1);      // LDS cursor
        if (idx < PERB)                                  // P(overflow) ~ 1e-30
            staged[(size_t)b * PERB + idx] =
                make_int2(cols[e] | (rl << 17), __float_as_int(vals[e]));
    }
}

// ------- exclusive scan of 1024 bucket counts -> bucketBase -------
__global__ __launch_bounds__(1024) void scan_buckets_kernel(
    const int* __restrict__ cursor, int* __restrict__ bucketBase)
{
    __shared__ int sm[NB];
    int t = threadIdx.x;
    int v = min(cursor[t * CPAD], PERB);
    sm[t] = v;
    __syncthreads();
    for (int off = 1; off < NB; off <<= 1) {
        int x = (t >= off) ? sm[t - off] : 0;
        __syncthreads();
        sm[t] += x;
        __syncthreads();
    }
    bucketBase[t] = sm[t] - v;
}

// ------- place: block per bucket; LDS histogram+scan -> CSR edges/rowPtr/cnt -------
__global__ __launch_bounds__(256) void place_kernel(
    const int* __restrict__ cursor, const int* __restrict__ bucketBase,
    const int2* __restrict__ staged, int2* __restrict__ edges,
    int* __restrict__ rowPtr, int* __restrict__ cnt, int n, int per_rows)
{
    __shared__ int hist[128];
    __shared__ int scn[128];
    __shared__ int lcnt[128];
    int b = blockIdx.x;
    int t = threadIdx.x;
    int r0 = b * per_rows;
    if (r0 >= n) return;
    if (t < 128) { hist[t] = 0; lcnt[t] = 0; }
    __syncthreads();
    int count = min(cursor[b * CPAD], PERB);
    const int2* sb = staged + (size_t)b * PERB;
    for (int i = t; i < count; i += 256)
        atomicAdd(&hist[((unsigned)sb[i].x) >> 17], 1);
    __syncthreads();
    if (t < 128) scn[t] = hist[t];
    __syncthreads();
    for (int off = 1; off < 128; off <<= 1) {
        int x = (t < 128 && t >= off) ? scn[t - off] : 0;
        __syncthreads();
        if (t < 128) scn[t] += x;
        __syncthreads();
    }
    int base = bucketBase[b];
    if (t < per_rows && r0 + t < n) {
        rowPtr[r0 + t] = base + scn[t] - hist[t];   // exclusive
        cnt[r0 + t] = hist[t];
    }
    __syncthreads();
    for (int i = t; i < count; i += 256) {
        int2 en = sb[i];
        int rl = ((unsigned)en.x) >> 17;
        int idx = atomicAdd(&lcnt[rl], 1);
        edges[base + scn[rl] - hist[rl] + idx] = make_int2(en.x & 0x1FFFF, en.y);
    }
}

// ------- gather-reduce: 2 edges per wave (half-wave each, uint2 gathers). -------
__global__ __launch_bounds__(256) void aggregate_kernel(
    const unsigned* __restrict__ xin,
    const int* __restrict__ rowPtr, const int* __restrict__ cnt,
    const int2* __restrict__ edges,
    unsigned* __restrict__ xout, int n)
{
    int wave = (blockIdx.x * 256 + threadIdx.x) >> 6;
    if (wave >= n) return;
    int lane = threadIdx.x & 63;
    int half = lane >> 5;
    int ll = lane & 31;
    const uint2* xin2 = (const uint2*)xin;      // row stride 64 uint2
    int e = rowPtr[wave];
    int end = e + cnt[wave];
    float4 a0 = {0.f,0.f,0.f,0.f}, a1 = {0.f,0.f,0.f,0.f};
    float4 a2 = {0.f,0.f,0.f,0.f}, a3 = {0.f,0.f,0.f,0.f};

#define ACC4(acc, pp, vv) { \
        acc.x += (vv) * bf2f((pp).x & 0xFFFF); \
        acc.y += (vv) * bf2f((pp).x >> 16); \
        acc.z += (vv) * bf2f((pp).y & 0xFFFF); \
        acc.w += (vv) * bf2f((pp).y >> 16); }

    if ((e & 1) && e < end) {
        int2 ed = edges[e];
        float v = half ? 0.f : __int_as_float(ed.y);
        uint2 p = xin2[(size_t)ed.x * 64 + ll];
        ACC4(a0, p, v);
        ++e;
    }
    for (; e + 7 < end; e += 8) {
        int4 q0 = *(const int4*)&edges[e];
        int4 q1 = *(const int4*)&edges[e + 2];
        int4 q2 = *(const int4*)&edges[e + 4];
        int4 q3 = *(const int4*)&edges[e + 6];
        int   c0 = half ? q0.z : q0.x;
        int   c1 = half ? q1.z : q1.x;
        int   c2 = half ? q2.z : q2.x;
        int   c3 = half ? q3.z : q3.x;
        float v0 = __int_as_float(half ? q0.w : q0.y);
        float v1 = __int_as_float(half ? q1.w : q1.y);
        float v2 = __int_as_float(half ? q2.w : q2.y);
        float v3 = __int_as_float(half ? q3.w : q3.y);
        uint2 p0 = xin2[(size_t)c0 * 64 + ll];
        uint2 p1 = xin2[(size_t)c1 * 64 + ll];
        uint2 p2 = xin2[(size_t)c2 * 64 + ll];
        uint2 p3 = xin2[(size_t)c3 * 64 + ll];
        ACC4(a0, p0, v0);
        ACC4(a1, p1, v1);
        ACC4(a2, p2, v2);
        ACC4(a3, p3, v3);
    }
    for (; e + 1 < end; e += 2) {
        int4 q0 = *(const int4*)&edges[e];
        int   c0 = half ? q0.z : q0.x;
        float v0 = __int_as_float(half ? q0.w : q0.y);
        uint2 p0 = xin2[(size_t)c0 * 64 + ll];
        ACC4(a0, p0, v0);
    }
    if (e < end) {
        int2 ed = edges[e];
        float v = half ? 0.f : __int_as_float(ed.y);
        uint2 p = xin2[(size_t)ed.x * 64 + ll];
        ACC4(a0, p, v);
    }
#undef ACC4

    a0.x += a1.x + a2.x + a3.x;
    a0.y += a1.y + a2.y + a3.y;
    a0.z += a1.z + a2.z + a3.z;
    a0.w += a1.w + a2.w + a3.w;
    float bx = __shfl(a0.x, ll + 32, 64);
    float by = __shfl(a0.y, ll + 32, 64);
    float bz = __shfl(a0.z, ll + 32, 64);
    float bw = __shfl(a0.w, ll + 32, 64);
    if (half == 0) {
        a0.x += bx; a0.y += by; a0.z += bz; a0.w += bw;
        uint2 pk;
        pk.x = f2bf(a0.x) | ((unsigned)f2bf(a0.y) << 16);
        pk.y = f2bf(a0.z) | ((unsigned)f2bf(a0.w) << 16);
        ((uint2*)xout)[(size_t)wave * 64 + 32 + ll] = pk;
    }
}

// ------------- column sums/sumsq of xbf, SLICED accumulators -------------
__global__ __launch_bounds__(256) void xstats_kernel(
    const u16* __restrict__ xbf, float* __restrict__ s1s, int n)
{
    int t = threadIdx.x;
    int r0 = blockIdx.x * STAT_ROWS;
    int r1 = min(n, r0 + STAT_ROWS);
    float s = 0.f, q = 0.f;
    for (int r = r0; r < r1; ++r) {
        float x = bf2f((unsigned)xbf[(size_t)r * 256 + t]);
        s += x; q += x * x;
    }
    float* base = s1s + (size_t)(blockIdx.x & (NS1 - 1)) * 512;
    atomicAdd(&base[t], s);
    atomicAdd(&base[256 + t], q);
}

// ------------- BN1 affine coefficients (reduces NS1 slices) -------------
__global__ __launch_bounds__(256) void prep1a_kernel(
    const float* __restrict__ s1s,
    const float* __restrict__ gamma1, const float* __restrict__ beta1,
    float* __restrict__ a1, float* __restrict__ c1, float n)
{
    int t = threadIdx.x;
    float sum = 0.f, sq = 0.f;
#pragma unroll
    for (int s = 0; s < NS1; ++s) {
        sum += s1s[s * 512 + t];
        sq  += s1s[s * 512 + 256 + t];
    }
    float mu = sum / n;
    float var = sq / n - mu * mu;
    float rs = rsqrtf(var + EPSV);
    float a = rs * gamma1[t];
    a1[t] = a;
    c1[t] = beta1[t] - mu * a;
}

// ------- W1bt[nIdx][k] = bf16(a1[k]*W1[k][nIdx]) ; b1p = c1@W1 + b1 -------
__global__ __launch_bounds__(256) void convw1_kernel(
    const float* __restrict__ W1, const float* __restrict__ a1,
    const float* __restrict__ c1, const float* __restrict__ b1,
    u16* __restrict__ W1bt, float* __restrict__ b1p)
{
    __shared__ float red[256];
    int nIdx = blockIdx.x;
    int k = threadIdx.x;
    float w = W1[(size_t)k * N_H + nIdx];
    W1bt[(size_t)nIdx * 256 + k] = f2bf(a1[k] * w);
    red[k] = c1[k] * w;
    __syncthreads();
    for (int s = 128; s > 0; s >>= 1) {
        if (k < s) red[k] += red[k + s];
        __syncthreads();
    }
    if (k == 0) b1p[nIdx] = red[0] + b1[nIdx];
}

// ------------- W2bt[nIdx][k] = bf16(W2[k][nIdx]) -------------
__global__ __launch_bounds__(256) void convw2_kernel(
    const float* __restrict__ W2, u16* __restrict__ W2bt)
{
    int nIdx = blockIdx.x;
    int k = threadIdx.x;
    W2bt[(size_t)nIdx * 256 + k] = f2bf(W2[(size_t)k * N_D + nIdx]);
}

// ------------- BN2 per-column affine (reduces NS2 slices) -------------
__global__ __launch_bounds__(256) void prep2_kernel(
    const float* __restrict__ s2s,
    const float* __restrict__ gamma2, const float* __restrict__ beta2,
    float* __restrict__ a2, float* __restrict__ c2, float n)
{
    int t = threadIdx.x;
    float sum = 0.f, sq = 0.f;
#pragma unroll
    for (int s = 0; s < NS2; ++s) {
        sum += s2s[s * 512 + t];
        sq  += s2s[s * 512 + 256 + t];
    }
    float mu = sum / n;
    float var = sq / n - mu * mu;
    float rs = rsqrtf(var + EPSV);
    float a = rs * gamma2[t];
    a2[t] = a;
    c2[t] = beta2[t] - mu * a;
}

// ------------- GEMM1: bulk-load K-half + sched_barrier(0) fence.
// R13 signature test FAILED: VGPR stayed 52 -> the LLVM scheduler sank the
// bulk loads back to just-before-use (register-pressure minimization),
// reconstructing ~48 serialized load->waitcnt->use chains per wave.
// sched_barrier(0) is a hard fence no instruction may cross: all 24 loads
// of a K-half must issue before its MFMAs, forcing their dest registers
// live (VGPR ~150 = the theory's observable signature) and paying global
// latency ~once per half instead of ~24x. -------------
__global__ __launch_bounds__(256, 3) void gemm1_kernel(
    const u16* __restrict__ xbf, const u16* __restrict__ W1bt,
    const float* __restrict__ b1p, u16* __restrict__ ybf,
    float* __restrict__ s2s, int n)
{
    __shared__ __align__(16) u16 T[64 * 136];   // +8 pad per row
    __shared__ float ssum[128];
    __shared__ float ssq[128];
    int t = threadIdx.x;
    int w = t >> 6, l = t & 63;
    int row0 = blockIdx.x * 64;
    int col0 = blockIdx.y * 128;
    int wrow = (w & 1) * 32, wcol = (w >> 1) * 64;
    int lm = l & 15, lq = l >> 4;
    if (t < 128) { ssum[t] = 0.f; ssq[t] = 0.f; }

    floatx4 acc[2][4];
#pragma unroll
    for (int i = 0; i < 2; ++i)
#pragma unroll
        for (int j = 0; j < 4; ++j) acc[i][j] = (floatx4){0.f, 0.f, 0.f, 0.f};

    const u16* Ab = xbf + (size_t)(row0 + wrow + lm) * 256 + lq * 8;
    const u16* Bb = W1bt + (size_t)(col0 + wcol + lm) * 256 + lq * 8;

#pragma unroll
    for (int h = 0; h < 2; ++h) {
        const int kh = h * 128;
        short8 aR[4][2], bR[4][4];
#pragma unroll
        for (int s = 0; s < 4; ++s) {
            int k = kh + s * 32;
            aR[s][0] = *(const short8*)&Ab[k];
            aR[s][1] = *(const short8*)&Ab[4096 + k];
            bR[s][0] = *(const short8*)&Bb[k];
            bR[s][1] = *(const short8*)&Bb[4096 + k];
            bR[s][2] = *(const short8*)&Bb[8192 + k];
            bR[s][3] = *(const short8*)&Bb[12288 + k];
        }
        __builtin_amdgcn_sched_barrier(0);   // loads above may NOT sink below
#pragma unroll
        for (int s = 0; s < 4; ++s)
#pragma unroll
            for (int fm = 0; fm < 2; ++fm)
#pragma unroll
                for (int fn = 0; fn < 4; ++fn)
                    acc[fm][fn] = __builtin_amdgcn_mfma_f32_16x16x32_bf16(
                        aR[s][fm], bR[s][fn], acc[fm][fn], 0, 0, 0);
    }

    __syncthreads();   // orders ssum/ssq init before atomics below
    float cs[4] = {0.f, 0.f, 0.f, 0.f};
    float cq[4] = {0.f, 0.f, 0.f, 0.f};
#pragma unroll
    for (int fn = 0; fn < 4; ++fn) {
        int cl = wcol + fn * 16 + lm;
        float bb = b1p[col0 + cl];
#pragma unroll
        for (int fm = 0; fm < 2; ++fm) {
            int rl = wrow + fm * 16 + lq * 4;
#pragma unroll
            for (int i = 0; i < 4; ++i) {
                float v = acc[fm][fn][i] + bb;
                T[(rl + i) * 136 + cl] = f2bf(v);
                if (row0 + rl + i < n) { cs[fn] += v; cq[fn] += v * v; }
            }
        }
        atomicAdd(&ssum[cl], cs[fn]);
        atomicAdd(&ssq[cl], cq[fn]);
    }
    __syncthreads();
    float* sbase = s2s + (size_t)(blockIdx.x & (NS2 - 1)) * 512;
    if (t < 128) {
        atomicAdd(&sbase[col0 + t], ssum[t]);
        atomicAdd(&sbase[256 + col0 + t], ssq[t]);
    }
    // coalesced writeback: 16 lanes x uint4 = one full 256B row-half per pass
#pragma unroll
    for (int p = 0; p < 4; ++p) {
        int r = p * 16 + (t >> 4);
        if (row0 + r < n)
            *(uint4*)&ybf[(size_t)(row0 + r) * 256 + col0 + (t & 15) * 8] =
                *(const uint4*)&T[r * 136 + (t & 15) * 8];
    }
}

__device__ __forceinline__ short8 bn_relu_pack(
    uint4 raw, float4 aa0, float4 aa1, float4 cc0, float4 cc1)
{
    float z0 = fmaxf(bf2f(raw.x & 0xFFFF) * aa0.x + cc0.x, 0.f);
    float z1 = fmaxf(bf2f(raw.x >> 16)    * aa0.y + cc0.y, 0.f);
    float z2 = fmaxf(bf2f(raw.y & 0xFFFF) * aa0.z + cc0.z, 0.f);
    float z3 = fmaxf(bf2f(raw.y >> 16)    * aa0.w + cc0.w, 0.f);
    float z4 = fmaxf(bf2f(raw.z & 0xFFFF) * aa1.x + cc1.x, 0.f);
    float z5 = fmaxf(bf2f(raw.z >> 16)    * aa1.y + cc1.y, 0.f);
    float z6 = fmaxf(bf2f(raw.w & 0xFFFF) * aa1.z + cc1.z, 0.f);
    float z7 = fmaxf(bf2f(raw.w >> 16)    * aa1.w + cc1.w, 0.f);
    uint4 pk;
    pk.x = f2bf(z0) | ((unsigned)f2bf(z1) << 16);
    pk.y = f2bf(z2) | ((unsigned)f2bf(z3) << 16);
    pk.z = f2bf(z4) | ((unsigned)f2bf(z5) << 16);
    pk.w = f2bf(z6) | ((unsigned)f2bf(z7) << 16);
    return *(short8*)&pk;
}

// ------------- GEMM2: bulk-load K-half + sched_barrier(0) fence,
// BN2+relu fused in-register. -------------
__global__ __launch_bounds__(256, 2) void gemm2_kernel(
    const u16* __restrict__ ybf, const u16* __restrict__ W2bt,
    const float* __restrict__ a2, const float* __restrict__ c2,
    const float* __restrict__ b2, float* __restrict__ out, int n)
{
    int t = threadIdx.x;
    int w = t >> 6, l = t & 63;
    int row0 = blockIdx.x * 64;
    int wrow = (w & 1) * 32, wcol = (w >> 1) * 64;
    int lm = l & 15, lq = l >> 4;

    floatx4 acc[2][4];
#pragma unroll
    for (int i = 0; i < 2; ++i)
#pragma unroll
        for (int j = 0; j < 4; ++j) acc[i][j] = (floatx4){0.f, 0.f, 0.f, 0.f};

    const u16* Ab = ybf + (size_t)(row0 + wrow + lm) * 256 + lq * 8;
    const u16* Bb = W2bt + (size_t)(wcol + lm) * 256 + lq * 8;
    int kbase = lq * 8;

#pragma unroll
    for (int h = 0; h < 2; ++h) {
        const int kh = h * 128;
        uint4 yR[4][2];
        short8 bR[4][4];
#pragma unroll
        for (int s = 0; s < 4; ++s) {
            int k = kh + s * 32;
            yR[s][0] = *(const uint4*)&Ab[k];
            yR[s][1] = *(const uint4*)&Ab[4096 + k];
            bR[s][0] = *(const short8*)&Bb[k];
            bR[s][1] = *(const short8*)&Bb[4096 + k];
            bR[s][2] = *(const short8*)&Bb[8192 + k];
            bR[s][3] = *(const short8*)&Bb[12288 + k];
        }
        __builtin_amdgcn_sched_barrier(0);   // loads above may NOT sink below
#pragma unroll
        for (int s = 0; s < 4; ++s) {
            int kc = kh + s * 32 + kbase;
            float4 aa0 = *(const float4*)&a2[kc];
            float4 aa1 = *(const float4*)&a2[kc + 4];
            float4 cc0 = *(const float4*)&c2[kc];
            float4 cc1 = *(const float4*)&c2[kc + 4];
            short8 af0 = bn_relu_pack(yR[s][0], aa0, aa1, cc0, cc1);
            short8 af1 = bn_relu_pack(yR[s][1], aa0, aa1, cc0, cc1);
#pragma unroll
            for (int fn = 0; fn < 4; ++fn) {
                acc[0][fn] = __builtin_amdgcn_mfma_f32_16x16x32_bf16(
                    af0, bR[s][fn], acc[0][fn], 0, 0, 0);
                acc[1][fn] = __builtin_amdgcn_mfma_f32_16x16x32_bf16(
                    af1, bR[s][fn], acc[1][fn], 0, 0, 0);
            }
        }
    }

#pragma unroll
    for (int fn = 0; fn < 4; ++fn) {
        int c = wcol + fn * 16 + lm;
        float bb = b2[c];
#pragma unroll
        for (int fm = 0; fm < 2; ++fm) {
            int rbase = row0 + wrow + fm * 16 + lq * 4;
#pragma unroll
            for (int i = 0; i < 4; ++i) {
                int r = rbase + i;
                if (r < n) out[(size_t)r * N_D + c] = acc[fm][fn][i] + bb;
            }
        }
    }
}

extern "C" void kernel_launch(void* const* d_in, const int* in_sizes, int n_in,
                              void* d_out, int out_size, void* d_ws, size_t ws_size,
                              hipStream_t stream)
{
    const float* input    = (const float*)d_in[0];
    const int*   adj_rows = (const int*)d_in[1];
    const int*   adj_cols = (const int*)d_in[2];
    const float* adj_vals = (const float*)d_in[3];
    const float* gamma1   = (const float*)d_in[4];
    const float* beta1    = (const float*)d_in[5];
    const float* W1       = (const float*)d_in[6];
    const float* b1       = (const float*)d_in[7];
    const float* gamma2   = (const float*)d_in[8];
    const float* beta2    = (const float*)d_in[9];
    const float* W2       = (const float*)d_in[10];
    const float* b2       = (const float*)d_in[11];

    int n = in_sizes[0] / N_D;   // 100000
    int E = in_sizes[1];         // 1600000
    size_t n_pad = ((size_t)n + 127) & ~(size_t)127;

    u16* xbf = (u16*)d_ws;                         // n_pad*256 bf16
    u16* ybf = xbf + n_pad * 256;                  // n_pad*256 bf16
    int2* edges = (int2*)ybf;                      // E int2 (aliases ybf; consumed pre-gemm1)
    int2* staged = edges + E;                      // NB*PERB int2 (also in ybf region)
    u16* W1bt = ybf + n_pad * 256;                 // 256*256 bf16
    u16* W2bt = W1bt + 256 * 256;                  // 128*256 bf16
    float* stats  = (float*)(W2bt + 128 * 256);
    float* a1     = stats;
    float* c1     = stats + 256;
    float* b1p    = stats + 512;
    float* a2     = stats + 768;
    float* c2     = stats + 1024;
    float* s1s    = stats + 1280;                  // NS1*512 floats
    float* s2s    = s1s + NS1 * 512;               // NS2*512 floats
    int* cursor     = (int*)(s2s + NS2 * 512);     // NB*CPAD ints (64B-padded)
    int* bucketBase = cursor + NB * CPAD;          // NB ints
    int* rowPtr     = bucketBase + NB;             // n ints
    int* cnt        = rowPtr + n;                  // n ints

    hipMemsetAsync(cursor, 0, (size_t)NB * CPAD * sizeof(int), stream);
    hipMemsetAsync(s1s, 0, (size_t)(NS1 + NS2) * 512 * sizeof(float), stream);

    convin_kernel<<<(n * 32 + 255) / 256, 256, 0, stream>>>(input, xbf, n);
    convw2_kernel<<<128, 256, 0, stream>>>(W2, W2bt);

    // bucket magic: b = umulhi(r, inv_pr) == r / per_rows for r < 2^17
    int per_rows = (n + NB - 1) / NB;                       // 98
    unsigned inv_pr = (unsigned)((((unsigned long long)1 << 32) + per_rows - 1) / per_rows);

    bucket_kernel<<<256, 1024, 0, stream>>>(
        adj_rows, adj_cols, adj_vals, cursor, staged, E, inv_pr, per_rows);
    scan_buckets_kernel<<<1, 1024, 0, stream>>>(cursor, bucketBase);
    place_kernel<<<NB, 256, 0, stream>>>(
        cursor, bucketBase, staged, edges, rowPtr, cnt, n, per_rows);

    aggregate_kernel<<<(n + 3) / 4, 256, 0, stream>>>(
        (const unsigned*)xbf, rowPtr, cnt, edges, (unsigned*)xbf, n);

    xstats_kernel<<<(n + STAT_ROWS - 1) / STAT_ROWS, 256, 0, stream>>>(xbf, s1s, n);

    prep1a_kernel<<<1, 256, 0, stream>>>(s1s, gamma1, beta1, a1, c1, (float)n);
    convw1_kernel<<<256, 256, 0, stream>>>(W1, a1, c1, b1, W1bt, b1p);

    dim3 g1((unsigned)(n_pad / 64), 2);
    gemm1_kernel<<<g1, 256, 0, stream>>>(xbf, W1bt, b1p, ybf, s2s, n);

    prep2_kernel<<<1, 256, 0, stream>>>(s2s, gamma2, beta2, a2, c2, (float)n);

    gemm2_kernel<<<(unsigned)(n_pad / 64), 256, 0, stream>>>(ybf, W2bt, a2, c2, b2, (float*)d_out, n);
}

// Round 15
// 426.110 us; speedup vs baseline: 1.1093x; 1.1063x over previous
//
#include <hip/hip_runtime.h>

#define N_D 128
#define N_H 256
#define EPSV 1e-5f
#define STAT_ROWS 256
#define NS1 16     // xstats slices
#define NS2 32     // gemm1-stats slices
#define NB 1024    // row-range buckets
#define PERB 2304  // staged capacity per bucket (mean 1563, +18 sigma)
#define CPAD 16    // cursor padding: one counter per 64B line

typedef unsigned short u16;
typedef __attribute__((ext_vector_type(8))) short short8;
typedef __attribute__((ext_vector_type(4))) float floatx4;

__device__ __forceinline__ float bf2f(unsigned u) {
    return __uint_as_float(u << 16);
}
__device__ __forceinline__ u16 f2bf(float f) {
    unsigned u = __float_as_uint(f);
    return (u16)((u + 0x7FFFu + ((u >> 16) & 1u)) >> 16);
}
__device__ __forceinline__ void load16_to_lds(const void* g, void* l) {
    auto gp = reinterpret_cast<const unsigned int __attribute__((address_space(1)))*>(
        reinterpret_cast<uintptr_t>(g));
    auto lp = reinterpret_cast<unsigned int __attribute__((address_space(3)))*>(
        reinterpret_cast<uintptr_t>(l));
    __builtin_amdgcn_global_load_lds(gp, lp, 16, 0, 0);
}

// ------- convert input fp32 -> xbf cols 0..127 (bf16); no atomics -------
__global__ __launch_bounds__(256) void convin_kernel(
    const float* __restrict__ input, u16* __restrict__ xbf, int n)
{
    int gid = blockIdx.x * 256 + threadIdx.x;
    if (gid < n * 32) {
        int r = gid >> 5, c4 = (gid & 31) * 4;
        float4 v = *(const float4*)&input[(size_t)r * N_D + c4];
        unsigned p0 = f2bf(v.x) | ((unsigned)f2bf(v.y) << 16);
        unsigned p1 = f2bf(v.z) | ((unsigned)f2bf(v.w) << 16);
        *(uint2*)&xbf[(size_t)r * 256 + c4] = make_uint2(p0, p1);
    }
}

// ------- bucket edges by row-range; ONE global atomic per (block,bucket). -------
__global__ __launch_bounds__(1024) void bucket_kernel(
    const int* __restrict__ rows, const int* __restrict__ cols,
    const float* __restrict__ vals, int* __restrict__ cursor,
    int2* __restrict__ staged, int E, unsigned inv_pr, int per_rows)
{
    __shared__ int hist[NB];
    __shared__ int base[NB];
    __shared__ int lcnt[NB];
    int t = threadIdx.x;
    hist[t] = 0;
    __syncthreads();
    int per = (E + (int)gridDim.x - 1) / (int)gridDim.x;
    int lo = blockIdx.x * per;
    int hi = min(E, lo + per);
    for (int e = lo + t; e < hi; e += 1024) {
        int b = (int)__umulhi((unsigned)rows[e], inv_pr);
        atomicAdd(&hist[b], 1);
    }
    __syncthreads();
    {
        int h = hist[t];
        base[t] = h ? atomicAdd(&cursor[t * CPAD], h) : 0;
        lcnt[t] = 0;
    }
    __syncthreads();
    for (int e = lo + t; e < hi; e += 1024) {
        int r = rows[e];
        int b = (int)__umulhi((unsigned)r, inv_pr);
        int rl = r - b * per_rows;                       // < 98, 7 bits
        int idx = base[b] + atomicAdd(&lcnt[b], 1);      // LDS cursor
        if (idx < PERB)                                  // P(overflow) ~ 1e-30
            staged[(size_t)b * PERB + idx] =
                make_int2(cols[e] | (rl << 17), __float_as_int(vals[e]));
    }
}

// ------- exclusive scan of 1024 bucket counts -> bucketBase -------
__global__ __launch_bounds__(1024) void scan_buckets_kernel(
    const int* __restrict__ cursor, int* __restrict__ bucketBase)
{
    __shared__ int sm[NB];
    int t = threadIdx.x;
    int v = min(cursor[t * CPAD], PERB);
    sm[t] = v;
    __syncthreads();
    for (int off = 1; off < NB; off <<= 1) {
        int x = (t >= off) ? sm[t - off] : 0;
        __syncthreads();
        sm[t] += x;
        __syncthreads();
    }
    bucketBase[t] = sm[t] - v;
}

// ------- place: block per bucket; LDS histogram+scan -> CSR edges/rowPtr/cnt -------
__global__ __launch_bounds__(256) void place_kernel(
    const int* __restrict__ cursor, const int* __restrict__ bucketBase,
    const int2* __restrict__ staged, int2* __restrict__ edges,
    int* __restrict__ rowPtr, int* __restrict__ cnt, int n, int per_rows)
{
    __shared__ int hist[128];
    __shared__ int scn[128];
    __shared__ int lcnt[128];
    int b = blockIdx.x;
    int t = threadIdx.x;
    int r0 = b * per_rows;
    if (r0 >= n) return;
    if (t < 128) { hist[t] = 0; lcnt[t] = 0; }
    __syncthreads();
    int count = min(cursor[b * CPAD], PERB);
    const int2* sb = staged + (size_t)b * PERB;
    for (int i = t; i < count; i += 256)
        atomicAdd(&hist[((unsigned)sb[i].x) >> 17], 1);
    __syncthreads();
    if (t < 128) scn[t] = hist[t];
    __syncthreads();
    for (int off = 1; off < 128; off <<= 1) {
        int x = (t < 128 && t >= off) ? scn[t - off] : 0;
        __syncthreads();
        if (t < 128) scn[t] += x;
        __syncthreads();
    }
    int base = bucketBase[b];
    if (t < per_rows && r0 + t < n) {
        rowPtr[r0 + t] = base + scn[t] - hist[t];   // exclusive
        cnt[r0 + t] = hist[t];
    }
    __syncthreads();
    for (int i = t; i < count; i += 256) {
        int2 en = sb[i];
        int rl = ((unsigned)en.x) >> 17;
        int idx = atomicAdd(&lcnt[rl], 1);
        edges[base + scn[rl] - hist[rl] + idx] = make_int2(en.x & 0x1FFFF, en.y);
    }
}

// ------- gather-reduce: 2 edges per wave (half-wave each, uint2 gathers). -------
__global__ __launch_bounds__(256) void aggregate_kernel(
    const unsigned* __restrict__ xin,
    const int* __restrict__ rowPtr, const int* __restrict__ cnt,
    const int2* __restrict__ edges,
    unsigned* __restrict__ xout, int n)
{
    int wave = (blockIdx.x * 256 + threadIdx.x) >> 6;
    if (wave >= n) return;
    int lane = threadIdx.x & 63;
    int half = lane >> 5;
    int ll = lane & 31;
    const uint2* xin2 = (const uint2*)xin;      // row stride 64 uint2
    int e = rowPtr[wave];
    int end = e + cnt[wave];
    float4 a0 = {0.f,0.f,0.f,0.f}, a1 = {0.f,0.f,0.f,0.f};
    float4 a2 = {0.f,0.f,0.f,0.f}, a3 = {0.f,0.f,0.f,0.f};

#define ACC4(acc, pp, vv) { \
        acc.x += (vv) * bf2f((pp).x & 0xFFFF); \
        acc.y += (vv) * bf2f((pp).x >> 16); \
        acc.z += (vv) * bf2f((pp).y & 0xFFFF); \
        acc.w += (vv) * bf2f((pp).y >> 16); }

    if ((e & 1) && e < end) {
        int2 ed = edges[e];
        float v = half ? 0.f : __int_as_float(ed.y);
        uint2 p = xin2[(size_t)ed.x * 64 + ll];
        ACC4(a0, p, v);
        ++e;
    }
    for (; e + 7 < end; e += 8) {
        int4 q0 = *(const int4*)&edges[e];
        int4 q1 = *(const int4*)&edges[e + 2];
        int4 q2 = *(const int4*)&edges[e + 4];
        int4 q3 = *(const int4*)&edges[e + 6];
        int   c0 = half ? q0.z : q0.x;
        int   c1 = half ? q1.z : q1.x;
        int   c2 = half ? q2.z : q2.x;
        int   c3 = half ? q3.z : q3.x;
        float v0 = __int_as_float(half ? q0.w : q0.y);
        float v1 = __int_as_float(half ? q1.w : q1.y);
        float v2 = __int_as_float(half ? q2.w : q2.y);
        float v3 = __int_as_float(half ? q3.w : q3.y);
        uint2 p0 = xin2[(size_t)c0 * 64 + ll];
        uint2 p1 = xin2[(size_t)c1 * 64 + ll];
        uint2 p2 = xin2[(size_t)c2 * 64 + ll];
        uint2 p3 = xin2[(size_t)c3 * 64 + ll];
        ACC4(a0, p0, v0);
        ACC4(a1, p1, v1);
        ACC4(a2, p2, v2);
        ACC4(a3, p3, v3);
    }
    for (; e + 1 < end; e += 2) {
        int4 q0 = *(const int4*)&edges[e];
        int   c0 = half ? q0.z : q0.x;
        float v0 = __int_as_float(half ? q0.w : q0.y);
        uint2 p0 = xin2[(size_t)c0 * 64 + ll];
        ACC4(a0, p0, v0);
    }
    if (e < end) {
        int2 ed = edges[e];
        float v = half ? 0.f : __int_as_float(ed.y);
        uint2 p = xin2[(size_t)ed.x * 64 + ll];
        ACC4(a0, p, v);
    }
#undef ACC4

    a0.x += a1.x + a2.x + a3.x;
    a0.y += a1.y + a2.y + a3.y;
    a0.z += a1.z + a2.z + a3.z;
    a0.w += a1.w + a2.w + a3.w;
    float bx = __shfl(a0.x, ll + 32, 64);
    float by = __shfl(a0.y, ll + 32, 64);
    float bz = __shfl(a0.z, ll + 32, 64);
    float bw = __shfl(a0.w, ll + 32, 64);
    if (half == 0) {
        a0.x += bx; a0.y += by; a0.z += bz; a0.w += bw;
        uint2 pk;
        pk.x = f2bf(a0.x) | ((unsigned)f2bf(a0.y) << 16);
        pk.y = f2bf(a0.z) | ((unsigned)f2bf(a0.w) << 16);
        ((uint2*)xout)[(size_t)wave * 64 + 32 + ll] = pk;
    }
}

// ------------- column sums/sumsq of xbf, SLICED accumulators -------------
__global__ __launch_bounds__(256) void xstats_kernel(
    const u16* __restrict__ xbf, float* __restrict__ s1s, int n)
{
    int t = threadIdx.x;
    int r0 = blockIdx.x * STAT_ROWS;
    int r1 = min(n, r0 + STAT_ROWS);
    float s = 0.f, q = 0.f;
    for (int r = r0; r < r1; ++r) {
        float x = bf2f((unsigned)xbf[(size_t)r * 256 + t]);
        s += x; q += x * x;
    }
    float* base = s1s + (size_t)(blockIdx.x & (NS1 - 1)) * 512;
    atomicAdd(&base[t], s);
    atomicAdd(&base[256 + t], q);
}

// ------------- BN1 affine coefficients (reduces NS1 slices) -------------
__global__ __launch_bounds__(256) void prep1a_kernel(
    const float* __restrict__ s1s,
    const float* __restrict__ gamma1, const float* __restrict__ beta1,
    float* __restrict__ a1, float* __restrict__ c1, float n)
{
    int t = threadIdx.x;
    float sum = 0.f, sq = 0.f;
#pragma unroll
    for (int s = 0; s < NS1; ++s) {
        sum += s1s[s * 512 + t];
        sq  += s1s[s * 512 + 256 + t];
    }
    float mu = sum / n;
    float var = sq / n - mu * mu;
    float rs = rsqrtf(var + EPSV);
    float a = rs * gamma1[t];
    a1[t] = a;
    c1[t] = beta1[t] - mu * a;
}

// ------- W1bt[nIdx][k] = bf16(a1[k]*W1[k][nIdx]) ; b1p = c1@W1 + b1 -------
__global__ __launch_bounds__(256) void convw1_kernel(
    const float* __restrict__ W1, const float* __restrict__ a1,
    const float* __restrict__ c1, const float* __restrict__ b1,
    u16* __restrict__ W1bt, float* __restrict__ b1p)
{
    __shared__ float red[256];
    int nIdx = blockIdx.x;
    int k = threadIdx.x;
    float w = W1[(size_t)k * N_H + nIdx];
    W1bt[(size_t)nIdx * 256 + k] = f2bf(a1[k] * w);
    red[k] = c1[k] * w;
    __syncthreads();
    for (int s = 128; s > 0; s >>= 1) {
        if (k < s) red[k] += red[k + s];
        __syncthreads();
    }
    if (k == 0) b1p[nIdx] = red[0] + b1[nIdx];
}

// ------------- W2bt[nIdx][k] = bf16(W2[k][nIdx]) -------------
__global__ __launch_bounds__(256) void convw2_kernel(
    const float* __restrict__ W2, u16* __restrict__ W2bt)
{
    int nIdx = blockIdx.x;
    int k = threadIdx.x;
    W2bt[(size_t)nIdx * 256 + k] = f2bf(W2[(size_t)k * N_D + nIdx]);
}

// ------------- BN2 per-column affine (reduces NS2 slices) -------------
__global__ __launch_bounds__(256) void prep2_kernel(
    const float* __restrict__ s2s,
    const float* __restrict__ gamma2, const float* __restrict__ beta2,
    float* __restrict__ a2, float* __restrict__ c2, float n)
{
    int t = threadIdx.x;
    float sum = 0.f, sq = 0.f;
#pragma unroll
    for (int s = 0; s < NS2; ++s) {
        sum += s2s[s * 512 + t];
        sq  += s2s[s * 512 + 256 + t];
    }
    float mu = sum / n;
    float var = sq / n - mu * mu;
    float rs = rsqrtf(var + EPSV);
    float a = rs * gamma2[t];
    a2[t] = a;
    c2[t] = beta2[t] - mu * a;
}

// ======== GEMM rewrite: all six prior variants (80-97us invariant) issued
// 16-scattered-line wave loads/stores. Here ALL global traffic is
// stream-contiguous: A (64 contiguous rows = 32KB block) + B staged via
// global_load_lds with pre-swizzled per-lane SOURCE (m201 pattern) into
// XOR-swizzled LDS (slot ^= row&15 -> frag ds_read_b128 2-way = free);
// outputs leave through swizzled T buffers as full-line stores. ========

// swizzled u16 index within a [rows][256 u16] LDS tile
__device__ __forceinline__ int swzA(int row, int c16) {
    return (row << 8) + (((c16) ^ (row & 15)) << 3);
}

// stage one [rows x 512B] contiguous global tile into swizzled LDS via
// global_load_lds: dest linear (wave-uniform base + lane*16), source
// pre-swizzled per lane so that swizzled layout lands in linear dest.
__device__ __forceinline__ void stage_swz(
    const u16* __restrict__ g, u16* lds, int t, int nu4)  // nu4 = rows*32
{
    for (int base = 0; base < nu4; base += 256) {
        int idx = base + t;                 // uint4 linear index
        int row = idx >> 5;
        int c16 = (idx & 31) ^ (row & 15);  // source column for this dest slot
        load16_to_lds(g + (size_t)row * 256 + c16 * 8,
                      &lds[(size_t)(base + (t & 192)) * 8]);
    }
}

// ------------- GEMM1: 64 rows x 256 cols/block, 4 col-chunks of 64.
// A staged once (coalesced), B chunk restaged from L2. -------------
__global__ __launch_bounds__(256, 2) void gemm1_kernel(
    const u16* __restrict__ xbf, const u16* __restrict__ W1bt,
    const float* __restrict__ b1p, u16* __restrict__ ybf,
    float* __restrict__ s2s, int n)
{
    __shared__ __align__(16) u16 As[64 * 256];   // 32KB swizzled
    __shared__ __align__(16) u16 Bs[64 * 256];   // 32KB swizzled
    __shared__ __align__(16) u16 T[64 * 64];     // 8KB, 16B-slot swizzled
    __shared__ float ssum[64];
    __shared__ float ssq[64];
    int t = threadIdx.x;
    int w = t >> 6, l = t & 63;
    int row0 = blockIdx.x * 64;
    int wrow = (w & 1) * 32, wcol = (w >> 1) * 32;
    int lm = l & 15, lq = l >> 4;

    stage_swz(xbf + (size_t)row0 * 256, As, t, 2048);
    stage_swz(W1bt, Bs, t, 2048);
    if (t < 64) { ssum[t] = 0.f; ssq[t] = 0.f; }
    __syncthreads();

    for (int c = 0; c < 4; ++c) {
        int col0g = c * 64;
        floatx4 acc[2][2];
#pragma unroll
        for (int i = 0; i < 2; ++i)
#pragma unroll
            for (int j = 0; j < 2; ++j) acc[i][j] = (floatx4){0.f,0.f,0.f,0.f};
#pragma unroll
        for (int ks = 0; ks < 8; ++ks) {
            short8 af[2], bfr[2];
#pragma unroll
            for (int f = 0; f < 2; ++f) {
                int ar = wrow + f * 16 + lm;
                af[f]  = *(const short8*)&As[swzA(ar, ks * 4 + lq)];
                int br = wcol + f * 16 + lm;
                bfr[f] = *(const short8*)&Bs[swzA(br, ks * 4 + lq)];
            }
#pragma unroll
            for (int fm = 0; fm < 2; ++fm)
#pragma unroll
                for (int fn = 0; fn < 2; ++fn)
                    acc[fm][fn] = __builtin_amdgcn_mfma_f32_16x16x32_bf16(
                        af[fm], bfr[fn], acc[fm][fn], 0, 0, 0);
        }
        // epilogue compute: T (swizzled 16B slots) + stats
#pragma unroll
        for (int fn = 0; fn < 2; ++fn) {
            int cl = wcol + fn * 16 + lm;
            float bb = b1p[col0g + cl];
            float cs = 0.f, cq = 0.f;
#pragma unroll
            for (int fm = 0; fm < 2; ++fm) {
                int rl = wrow + fm * 16 + lq * 4;
#pragma unroll
                for (int i = 0; i < 4; ++i) {
                    float v = acc[fm][fn][i] + bb;
                    int r = rl + i;
                    T[(r << 6) + ((((cl >> 3) ^ (r & 7)) << 3) | (cl & 7))] = f2bf(v);
                    if (row0 + r < n) { cs += v; cq += v * v; }
                }
            }
            atomicAdd(&ssum[cl], cs);
            atomicAdd(&ssq[cl], cq);
        }
        __syncthreads();
        // writeback (coalesced full-line) + flush stats + stage next B chunk
#pragma unroll
        for (int p = 0; p < 2; ++p) {
            int r = p * 32 + (t >> 3);
            int s = t & 7;
            if (row0 + r < n)
                *(uint4*)&ybf[(size_t)(row0 + r) * 256 + col0g + s * 8] =
                    *(const uint4*)&T[(r << 6) + ((s ^ (r & 7)) << 3)];
        }
        float* sbase = s2s + (size_t)(blockIdx.x & (NS2 - 1)) * 512;
        if (t < 64) {
            atomicAdd(&sbase[col0g + t], ssum[t]);
            atomicAdd(&sbase[256 + col0g + t], ssq[t]);
            ssum[t] = 0.f; ssq[t] = 0.f;
        }
        if (c < 3)
            stage_swz(W1bt + (size_t)(c + 1) * 64 * 256, Bs, t, 2048);
        __syncthreads();
    }
}

__device__ __forceinline__ short8 bn_relu_pack(
    uint4 raw, float4 aa0, float4 aa1, float4 cc0, float4 cc1)
{
    float z0 = fmaxf(bf2f(raw.x & 0xFFFF) * aa0.x + cc0.x, 0.f);
    float z1 = fmaxf(bf2f(raw.x >> 16)    * aa0.y + cc0.y, 0.f);
    float z2 = fmaxf(bf2f(raw.y & 0xFFFF) * aa0.z + cc0.z, 0.f);
    float z3 = fmaxf(bf2f(raw.y >> 16)    * aa0.w + cc0.w, 0.f);
    float z4 = fmaxf(bf2f(raw.z & 0xFFFF) * aa1.x + cc1.x, 0.f);
    float z5 = fmaxf(bf2f(raw.z >> 16)    * aa1.y + cc1.y, 0.f);
    float z6 = fmaxf(bf2f(raw.w & 0xFFFF) * aa1.z + cc1.z, 0.f);
    float z7 = fmaxf(bf2f(raw.w >> 16)    * aa1.w + cc1.w, 0.f);
    uint4 pk;
    pk.x = f2bf(z0) | ((unsigned)f2bf(z1) << 16);
    pk.y = f2bf(z2) | ((unsigned)f2bf(z3) << 16);
    pk.z = f2bf(z4) | ((unsigned)f2bf(z5) << 16);
    pk.w = f2bf(z6) | ((unsigned)f2bf(z7) << 16);
    return *(short8*)&pk;
}

// ------------- GEMM2: 64 rows x 128 cols/block, 4 col-chunks of 32.
// BN2+relu applied ONCE during (reg-staged, coalesced) A staging; inner
// loop is pure ds_read+MFMA. fp32 out via swizzled f32 T, full-line. -------------
__global__ __launch_bounds__(256, 2) void gemm2_kernel(
    const u16* __restrict__ ybf, const u16* __restrict__ W2bt,
    const float* __restrict__ a2, const float* __restrict__ c2,
    const float* __restrict__ b2, float* __restrict__ out, int n)
{
    __shared__ __align__(16) u16 As[64 * 256];   // 32KB swizzled (activated)
    __shared__ __align__(16) u16 Bs[32 * 256];   // 16KB swizzled
    __shared__ __align__(16) float Tf[64 * 32];  // 8KB, 16B-slot swizzled
    int t = threadIdx.x;
    int w = t >> 6, l = t & 63;
    int row0 = blockIdx.x * 64;
    int wrow = (w & 1) * 32, wcol16 = (w >> 1) * 16;
    int lm = l & 15, lq = l >> 4;

    // stage A: coalesced uint4 read + BN+relu + swizzled ds_write
    {
        const uint4* src = (const uint4*)(ybf + (size_t)row0 * 256);
#pragma unroll
        for (int p = 0; p < 8; ++p) {
            int idx = p * 256 + t;
            int row = idx >> 5;
            int c16 = idx & 31;
            uint4 raw = src[idx];
            float4 aa0 = *(const float4*)&a2[c16 * 8];
            float4 aa1 = *(const float4*)&a2[c16 * 8 + 4];
            float4 cc0 = *(const float4*)&c2[c16 * 8];
            float4 cc1 = *(const float4*)&c2[c16 * 8 + 4];
            short8 z = bn_relu_pack(raw, aa0, aa1, cc0, cc1);
            *(short8*)&As[swzA(row, c16)] = z;
        }
    }
    stage_swz(W2bt, Bs, t, 1024);
    __syncthreads();

    for (int c = 0; c < 4; ++c) {
        int col0g = c * 32;
        floatx4 acc[2];
        acc[0] = (floatx4){0.f,0.f,0.f,0.f};
        acc[1] = (floatx4){0.f,0.f,0.f,0.f};
#pragma unroll
        for (int ks = 0; ks < 8; ++ks) {
            short8 af[2], bfr;
#pragma unroll
            for (int f = 0; f < 2; ++f) {
                int ar = wrow + f * 16 + lm;
                af[f] = *(const short8*)&As[swzA(ar, ks * 4 + lq)];
            }
            int br = wcol16 + lm;
            bfr = *(const short8*)&Bs[swzA(br, ks * 4 + lq)];
#pragma unroll
            for (int fm = 0; fm < 2; ++fm)
                acc[fm] = __builtin_amdgcn_mfma_f32_16x16x32_bf16(
                    af[fm], bfr, acc[fm], 0, 0, 0);
        }
        // epilogue: swizzled f32 T write
        {
            int cl = wcol16 + lm;
            float bb = b2[col0g + cl];
#pragma unroll
            for (int fm = 0; fm < 2; ++fm) {
                int rl = wrow + fm * 16 + lq * 4;
#pragma unroll
                for (int i = 0; i < 4; ++i) {
                    int r = rl + i;
                    Tf[(r << 5) + ((((cl >> 2) ^ (r & 7)) << 2) | (cl & 3))] =
                        acc[fm][i] + bb;
                }
            }
        }
        __syncthreads();
        // coalesced writeback: float4 full-line
#pragma unroll
        for (int p = 0; p < 2; ++p) {
            int r = p * 32 + (t >> 3);
            int s = t & 7;
            if (row0 + r < n)
                *(float4*)&out[(size_t)(row0 + r) * N_D + col0g + s * 4] =
                    *(const float4*)&Tf[(r << 5) + ((s ^ (r & 7)) << 2)];
        }
        if (c < 3)
            stage_swz(W2bt + (size_t)(c + 1) * 32 * 256, Bs, t, 1024);
        __syncthreads();
    }
}

extern "C" void kernel_launch(void* const* d_in, const int* in_sizes, int n_in,
                              void* d_out, int out_size, void* d_ws, size_t ws_size,
                              hipStream_t stream)
{
    const float* input    = (const float*)d_in[0];
    const int*   adj_rows = (const int*)d_in[1];
    const int*   adj_cols = (const int*)d_in[2];
    const float* adj_vals = (const float*)d_in[3];
    const float* gamma1   = (const float*)d_in[4];
    const float* beta1    = (const float*)d_in[5];
    const float* W1       = (const float*)d_in[6];
    const float* b1       = (const float*)d_in[7];
    const float* gamma2   = (const float*)d_in[8];
    const float* beta2    = (const float*)d_in[9];
    const float* W2       = (const float*)d_in[10];
    const float* b2       = (const float*)d_in[11];

    int n = in_sizes[0] / N_D;   // 100000
    int E = in_sizes[1];         // 1600000
    size_t n_pad = ((size_t)n + 127) & ~(size_t)127;

    u16* xbf = (u16*)d_ws;                         // n_pad*256 bf16
    u16* ybf = xbf + n_pad * 256;                  // n_pad*256 bf16
    int2* edges = (int2*)ybf;                      // E int2 (aliases ybf; consumed pre-gemm1)
    int2* staged = edges + E;                      // NB*PERB int2 (also in ybf region)
    u16* W1bt = ybf + n_pad * 256;                 // 256*256 bf16
    u16* W2bt = W1bt + 256 * 256;                  // 128*256 bf16
    float* stats  = (float*)(W2bt + 128 * 256);
    float* a1     = stats;
    float* c1     = stats + 256;
    float* b1p    = stats + 512;
    float* a2     = stats + 768;
    float* c2     = stats + 1024;
    float* s1s    = stats + 1280;                  // NS1*512 floats
    float* s2s    = s1s + NS1 * 512;               // NS2*512 floats
    int* cursor     = (int*)(s2s + NS2 * 512);     // NB*CPAD ints (64B-padded)
    int* bucketBase = cursor + NB * CPAD;          // NB ints
    int* rowPtr     = bucketBase + NB;             // n ints
    int* cnt        = rowPtr + n;                  // n ints

    hipMemsetAsync(cursor, 0, (size_t)NB * CPAD * sizeof(int), stream);
    hipMemsetAsync(s1s, 0, (size_t)(NS1 + NS2) * 512 * sizeof(float), stream);

    convin_kernel<<<(n * 32 + 255) / 256, 256, 0, stream>>>(input, xbf, n);
    convw2_kernel<<<128, 256, 0, stream>>>(W2, W2bt);

    // bucket magic: b = umulhi(r, inv_pr) == r / per_rows for r < 2^17
    int per_rows = (n + NB - 1) / NB;                       // 98
    unsigned inv_pr = (unsigned)((((unsigned long long)1 << 32) + per_rows - 1) / per_rows);

    bucket_kernel<<<256, 1024, 0, stream>>>(
        adj_rows, adj_cols, adj_vals, cursor, staged, E, inv_pr, per_rows);
    scan_buckets_kernel<<<1, 1024, 0, stream>>>(cursor, bucketBase);
    place_kernel<<<NB, 256, 0, stream>>>(
        cursor, bucketBase, staged, edges, rowPtr, cnt, n, per_rows);

    aggregate_kernel<<<(n + 3) / 4, 256, 0, stream>>>(
        (const unsigned*)xbf, rowPtr, cnt, edges, (unsigned*)xbf, n);

    xstats_kernel<<<(n + STAT_ROWS - 1) / STAT_ROWS, 256, 0, stream>>>(xbf, s1s, n);

    prep1a_kernel<<<1, 256, 0, stream>>>(s1s, gamma1, beta1, a1, c1, (float)n);
    convw1_kernel<<<256, 256, 0, stream>>>(W1, a1, c1, b1, W1bt, b1p);

    gemm1_kernel<<<(unsigned)(n_pad / 64), 256, 0, stream>>>(xbf, W1bt, b1p, ybf, s2s, n);

    prep2_kernel<<<1, 256, 0, stream>>>(s2s, gamma2, beta2, a2, c2, (float)n);

    gemm2_kernel<<<(unsigned)(n_pad / 64), 256, 0, stream>>>(ybf, W2bt, a2, c2, b2, (float*)d_out, n);
}